// Round 2
// baseline (207.475 us; speedup 1.0000x reference)
//
#include <hip/hip_runtime.h>
#include <math.h>

#define LEAK 0.01f

typedef float v2f __attribute__((ext_vector_type(2)));

__device__ __forceinline__ float lrelu(float x) { return fmaxf(x, LEAK * x); }
__device__ __forceinline__ float fast_rcp(float x) { return __builtin_amdgcn_rcpf(x); }
__device__ __forceinline__ float sigmoid_f(float x) {
    return fast_rcp(1.0f + exp2f(-1.44269504f * x));
}
__device__ __forceinline__ float tanh_f(float x) {
    return 2.0f * fast_rcp(1.0f + exp2f(-2.88539008f * x)) - 1.0f;
}

// dot of 10 via 5 packed v_pk_fma_f32
__device__ __forceinline__ float dot10(const v2f w[5], const float h[10]) {
    v2f acc = w[0] * (v2f){h[0], h[1]};
    acc += w[1] * (v2f){h[2], h[3]};
    acc += w[2] * (v2f){h[4], h[5]};
    acc += w[3] * (v2f){h[6], h[7]};
    acc += w[4] * (v2f){h[8], h[9]};
    return acc.x + acc.y;
}

#define L1C 508
#define L1P 170
#define L2C 166
#define L2P 56
#define L3C 52
#define L3P 18
#define TT 18

// ---------------------------------------------------------------------------
// K1: per-flow conv1d x3 (+lrelu, +maxpool3 fused; pool windows are disjoint)
// one block = one flow. Sliding-window register reuse for conv1; float2 row
// loads + packed-FMA channel pairs for conv2/conv3.
// ---------------------------------------------------------------------------
__global__ __launch_bounds__(256) void conv_kernel(
    const float* __restrict__ in,
    const float* __restrict__ W1, const float* __restrict__ b1,
    const float* __restrict__ W2, const float* __restrict__ b2,
    const float* __restrict__ W3, const float* __restrict__ b3,
    float* __restrict__ xseq)
{
    __shared__ __align__(16) float xsraw[24 + 1536 + 24];
    __shared__ __align__(16) float y1raw[16 + L1P * 10 + 32];
    __shared__ __align__(16) float y2raw[8 + L2P * 6 + 24];
    float* xs = xsraw + 24;   // xs[l*3+p]
    float* y1 = y1raw + 16;   // y1[o*10+co]
    float* y2 = y2raw + 8;    // y2[o*6+co]  (stride 6 for b64-aligned rows)

    const int tid = threadIdx.x;
    const int b = blockIdx.x;

    { // load input, 1536 floats, coalesced float4
        const float4* src = (const float4*)(in + (size_t)b * 1536);
        float4* dst4 = (float4*)xs;
        for (int i = tid; i < 384; i += 256) dst4[i] = src[i];
    }
    __syncthreads();

    // ---- conv1 (3->10, k5) + lrelu + pool3 -> y1[170][10] ----
    // thread (co, ob) handles 7 CONSECUTIVE pool outputs with a sliding
    // 21-float window (9 new LDS reads per step instead of 21).
    {
        const int co = tid % 10;
        const int ob = tid / 10;            // 0..24 for tid<250
        if (tid < 250) {
            float w[15];
            #pragma unroll
            for (int q = 0; q < 15; ++q) w[q] = W1[co * 15 + q];
            const float bias = b1[co];
            const int o0 = ob * 7;
            int sb = 3 * o0 - 1;            // window start tap
            float win[21];                  // taps (sb+m, p) at win[3m+p]
            #pragma unroll
            for (int q = 0; q < 21; ++q) win[q] = xs[3 * sb + q];
            #pragma unroll
            for (int r = 0; r < 7; ++r) {
                const int o = o0 + r;
                if (o < L1P) {
                    float a0 = bias, a1 = bias, a2 = bias;
                    #pragma unroll
                    for (int p = 0; p < 3; ++p) {
                        #pragma unroll
                        for (int k = 0; k < 5; ++k) {
                            const float wv = w[p * 5 + k];
                            a0 = fmaf(wv, win[3 * k + p], a0);
                            a1 = fmaf(wv, win[3 * (k + 1) + p], a1);
                            a2 = fmaf(wv, win[3 * (k + 2) + p], a2);
                        }
                    }
                    float best = -3.0e38f;
                    if (sb >= 0)        best = fmaxf(best, lrelu(a0));
                    best = fmaxf(best, lrelu(a1));
                    if (sb + 2 < L1C)   best = fmaxf(best, lrelu(a2));
                    y1[o * 10 + co] = best;
                }
                if (r < 6 && o + 1 < L1P) {
                    #pragma unroll
                    for (int q = 0; q < 12; ++q) win[q] = win[q + 9];
                    #pragma unroll
                    for (int q = 0; q < 9; ++q) win[12 + q] = xs[3 * sb + 21 + q];
                    sb += 3;
                }
            }
        }
    }
    __syncthreads();

    // ---- conv2 (10->5, k5) + lrelu + pool3 -> y2[56][6-stride] ----
    // float2 row loads; channel-paired packed FMAs.
    {
        const int co = tid % 5;
        const int ob = tid / 5;             // 0..50 for tid<255
        v2f wv2[25];                        // wv2[c2*5+k] = (w[2c2][k], w[2c2+1][k])
        #pragma unroll
        for (int c2 = 0; c2 < 5; ++c2)
            #pragma unroll
            for (int k = 0; k < 5; ++k)
                wv2[c2 * 5 + k] = (v2f){W2[co * 50 + (2 * c2) * 5 + k],
                                        W2[co * 50 + (2 * c2 + 1) * 5 + k]};
        const float bias = b2[co];
        if (tid < 255) {
            for (int r = 0; r < 2; ++r) {
                const int o = ob + 51 * r;
                if (o < L2P) {
                    const int t0 = 3 * o - 1;
                    v2f rows[7][5];
                    #pragma unroll
                    for (int m = 0; m < 7; ++m) {
                        const v2f* pr = (const v2f*)(y1 + (t0 + m) * 10);
                        #pragma unroll
                        for (int c2 = 0; c2 < 5; ++c2) rows[m][c2] = pr[c2];
                    }
                    v2f v0 = {0.f, 0.f}, v1 = {0.f, 0.f}, v2 = {0.f, 0.f};
                    #pragma unroll
                    for (int c2 = 0; c2 < 5; ++c2) {
                        #pragma unroll
                        for (int k = 0; k < 5; ++k) {
                            const v2f wv = wv2[c2 * 5 + k];
                            v0 += wv * rows[k][c2];
                            v1 += wv * rows[k + 1][c2];
                            v2 += wv * rows[k + 2][c2];
                        }
                    }
                    const float a0 = bias + v0.x + v0.y;
                    const float a1 = bias + v1.x + v1.y;
                    const float a2 = bias + v2.x + v2.y;
                    float best = -3.0e38f;
                    if (t0 >= 0)        best = fmaxf(best, lrelu(a0));
                    best = fmaxf(best, lrelu(a1));
                    if (t0 + 2 < L2C)   best = fmaxf(best, lrelu(a2));
                    y2[o * 6 + co] = best;
                }
            }
        }
    }
    __syncthreads();

    // ---- conv3 (5->10, k5) + lrelu + pool3 -> xseq[b][t=o][j=co] ----
    {
        const int co = tid % 10;
        const int o = tid / 10;             // 0..25
        if (o < L3P) {
            v2f wv3[10];                    // pairs for ci {0,1},{2,3}
            float ws3[5];                   // ci = 4
            #pragma unroll
            for (int c2 = 0; c2 < 2; ++c2)
                #pragma unroll
                for (int k = 0; k < 5; ++k)
                    wv3[c2 * 5 + k] = (v2f){W3[co * 25 + (2 * c2) * 5 + k],
                                            W3[co * 25 + (2 * c2 + 1) * 5 + k]};
            #pragma unroll
            for (int k = 0; k < 5; ++k) ws3[k] = W3[co * 25 + 20 + k];
            const float bias = b3[co];
            const int t0 = 3 * o - 1;
            v2f ra[7][2];
            float rc[7];
            #pragma unroll
            for (int m = 0; m < 7; ++m) {
                const float* base = y2 + (t0 + m) * 6;
                ra[m][0] = ((const v2f*)base)[0];
                ra[m][1] = ((const v2f*)base)[1];
                rc[m] = base[4];
            }
            v2f v0 = {0.f, 0.f}, v1 = {0.f, 0.f}, v2 = {0.f, 0.f};
            float s0 = 0.f, s1 = 0.f, s2 = 0.f;
            #pragma unroll
            for (int c2 = 0; c2 < 2; ++c2) {
                #pragma unroll
                for (int k = 0; k < 5; ++k) {
                    const v2f wv = wv3[c2 * 5 + k];
                    v0 += wv * ra[k][c2];
                    v1 += wv * ra[k + 1][c2];
                    v2 += wv * ra[k + 2][c2];
                }
            }
            #pragma unroll
            for (int k = 0; k < 5; ++k) {
                s0 = fmaf(ws3[k], rc[k], s0);
                s1 = fmaf(ws3[k], rc[k + 1], s1);
                s2 = fmaf(ws3[k], rc[k + 2], s2);
            }
            const float a0 = bias + s0 + v0.x + v0.y;
            const float a1 = bias + s1 + v1.x + v1.y;
            const float a2 = bias + s2 + v2.x + v2.y;
            float best = -3.0e38f;
            if (t0 >= 0)        best = fmaxf(best, lrelu(a0));
            best = fmaxf(best, lrelu(a1));
            if (t0 + 2 < L3C)   best = fmaxf(best, lrelu(a2));
            xseq[(size_t)b * 180 + o * 10 + co] = best;
        }
    }
}

// ---------------------------------------------------------------------------
// K2: flow LSTM (3 layers, T=18, H=10) over 4096 flows.
// 16 lanes per flow; lane j owns hidden unit j (all 4 gates, packed dots).
// Recurrent h passes lane-to-lane via ONE bpermute round (no LDS round-trip
// in the chain); h history still written to LDS for the next layer's input.
// ---------------------------------------------------------------------------
__global__ __launch_bounds__(256) void flow_lstm_kernel(
    const float* __restrict__ xseq,
    const float* __restrict__ fWih, const float* __restrict__ fWhh,
    const float* __restrict__ fb,
    float* __restrict__ fv)
{
    __shared__ __align__(16) float sbuf[3][16 * 18 * 10];
    const int tid = threadIdx.x;
    const int blk = blockIdx.x;

    {
        const float* src = xseq + (size_t)blk * 2880;
        for (int i = tid; i < 2880; i += 256) sbuf[0][i] = src[i];
    }
    __syncthreads();

    const int el = tid >> 4;                 // local flow 0..15
    const int j = tid & 15;
    const int jj = (j < 10) ? j : 0;
    const int base = el * 180;
    const int lane = tid & 63;
    const int gbase = lane & 48;             // 16-lane group base within wave

    float fv_acc = 0.0f;

    for (int l = 0; l < 3; ++l) {
        const float* Wi = fWih + l * 400;
        const float* Wh = fWhh + l * 400;
        const float* bb = fb + l * 40;
        v2f wi0[5], wi1[5], wi2[5], wi3[5], wh0[5], wh1[5], wh2[5], wh3[5];
        #pragma unroll
        for (int k = 0; k < 5; ++k) {
            wi0[k] = ((const v2f*)(Wi + jj * 10))[k];
            wi1[k] = ((const v2f*)(Wi + (10 + jj) * 10))[k];
            wi2[k] = ((const v2f*)(Wi + (20 + jj) * 10))[k];
            wi3[k] = ((const v2f*)(Wi + (30 + jj) * 10))[k];
            wh0[k] = ((const v2f*)(Wh + jj * 10))[k];
            wh1[k] = ((const v2f*)(Wh + (10 + jj) * 10))[k];
            wh2[k] = ((const v2f*)(Wh + (20 + jj) * 10))[k];
            wh3[k] = ((const v2f*)(Wh + (30 + jj) * 10))[k];
        }
        const float bi = bb[jj], bf = bb[10 + jj], bg = bb[20 + jj], bo = bb[30 + jj];

        const float* inb = sbuf[l];
        float* outb = sbuf[(l + 1) % 3];
        float c = 0.0f, hj = 0.0f;
        float h[10], xc[10], xn[10];
        #pragma unroll
        for (int k = 0; k < 10; ++k) h[k] = 0.0f;
        {
            const v2f* p = (const v2f*)(inb + base);
            #pragma unroll
            for (int k = 0; k < 5; ++k) { v2f v = p[k]; xc[2*k] = v.x; xc[2*k+1] = v.y; }
        }

        for (int t = 0; t < TT; ++t) {
            if (t + 1 < TT) {               // prefetch x(t+1), consumed next step
                const v2f* p = (const v2f*)(inb + base + (t + 1) * 10);
                #pragma unroll
                for (int k = 0; k < 5; ++k) { v2f v = p[k]; xn[2*k] = v.x; xn[2*k+1] = v.y; }
            }
            float gi = bi + dot10(wi0, xc) + dot10(wh0, h);
            float gf = bf + dot10(wi1, xc) + dot10(wh1, h);
            float gg = bg + dot10(wi2, xc) + dot10(wh2, h);
            float go = bo + dot10(wi3, xc) + dot10(wh3, h);
            const float ai = sigmoid_f(gi), af = sigmoid_f(gf);
            const float ag = tanh_f(gg),    ao = sigmoid_f(go);
            c = af * c + ai * ag;
            hj = ao * tanh_f(c);
            if (j < 10) outb[base + t * 10 + j] = hj;   // history for next layer
            #pragma unroll
            for (int k = 0; k < 10; ++k) h[k] = __shfl(hj, gbase + k);
            #pragma unroll
            for (int k = 0; k < 10; ++k) xc[k] = xn[k];
        }
        if (l >= 1) fv_acc += hj;
        __asm__ __volatile__("" ::: "memory");   // layer boundary: keep DS order
    }
    if (j < 10) fv[(size_t)(blk * 16 + el) * 10 + j] = fv_acc;
}

// ---------------------------------------------------------------------------
// K3: trace LSTM (3 layers, T=64, H=10) for 64 rows + fused per-row MLP.
// One wave per row; software-pipelined layers. Per tick, the three layers'
// reads are all last-tick state, so the tick is phase-fused: all dots ->
// all activations -> ONE gather round (9 bpermutes) -> updates -> ONE
// broadcast round (30 bpermutes). 2 DS latencies/tick instead of 6.
// ---------------------------------------------------------------------------
__global__ __launch_bounds__(64) void trace_mlp_kernel(
    const float* __restrict__ fv,
    const float* __restrict__ tWih, const float* __restrict__ tWhh,
    const float* __restrict__ tb,
    const float* __restrict__ L1W, const float* __restrict__ L1b,
    const float* __restrict__ L2W, const float* __restrict__ L2b,
    const float* __restrict__ L3W, const float* __restrict__ L3b,
    const float* __restrict__ L4W, const float* __restrict__ L4b,
    float* __restrict__ out)
{
    __shared__ __align__(16) float xrow[640];
    __shared__ __align__(16) float m1[128];
    __shared__ __align__(16) float m2b[256];
    __shared__ __align__(16) float m3[64];

    const int lane = threadIdx.x;
    const int ti = blockIdx.x;

    {
        const float4* src = (const float4*)(fv + (size_t)ti * 640);
        float4* dst = (float4*)xrow;
        for (int i = lane; i < 160; i += 64) dst[i] = src[i];
    }
    __asm__ __volatile__("" ::: "memory");   // same-wave DS ordering

    const int gt = lane / 10;                 // 0:i 1:f 2:g 3:o (lanes<40)
    const bool isg = (gt == 2);
    const float m2g = isg ? 2.0f : 1.0f;      // tanh(x)=2*sig(2x)-1
    const float am = isg ? 2.0f : 1.0f;
    const float ab = isg ? -1.0f : 0.0f;

    const int r = (lane < 40) ? lane : 0;
    v2f wi0[5], wh0[5], wi1[5], wh1[5], wi2[5], wh2[5];
    #pragma unroll
    for (int k = 0; k < 5; ++k) {
        wi0[k] = ((const v2f*)(tWih + r * 10))[k];
        wh0[k] = ((const v2f*)(tWhh + r * 10))[k];
        wi1[k] = ((const v2f*)(tWih + 400 + r * 10))[k];
        wh1[k] = ((const v2f*)(tWhh + 400 + r * 10))[k];
        wi2[k] = ((const v2f*)(tWih + 800 + r * 10))[k];
        wh2[k] = ((const v2f*)(tWhh + 800 + r * 10))[k];
    }
    const float bs0 = tb[r], bs1 = tb[40 + r], bs2 = tb[80 + r];

    float hb0[10], hb1[10], hb2[10];
    #pragma unroll
    for (int k = 0; k < 10; ++k) { hb0[k] = 0.0f; hb1[k] = 0.0f; hb2[k] = 0.0f; }
    float c0 = 0.0f, c1 = 0.0f, c2 = 0.0f;

    float xc[10], xn[10];
    auto loadx = [&](float* d, int t) __attribute__((always_inline)) {
        const v2f* p = (const v2f*)(xrow + t * 10);
        #pragma unroll
        for (int k = 0; k < 5; ++k) { v2f v = p[k]; d[2*k] = v.x; d[2*k+1] = v.y; }
    };
    auto cpx = [&]() __attribute__((always_inline)) {
        #pragma unroll
        for (int k = 0; k < 10; ++k) xc[k] = xn[k];
    };
    auto tick = [&](bool D0, bool D1, bool D2) __attribute__((always_inline)) {
        // phase 1: gate pre-activations (all reads are last-tick state)
        float g0f = 0.f, g1f = 0.f, g2f = 0.f;
        if (D2) g2f = bs2 + dot10(wi2, hb1) + dot10(wh2, hb2);
        if (D1) g1f = bs1 + dot10(wi1, hb0) + dot10(wh1, hb1);
        if (D0) g0f = bs0 + dot10(wi0, xc) + dot10(wh0, hb0);
        // phase 2: activations
        float a0 = 0.f, a1 = 0.f, a2 = 0.f;
        if (D2) a2 = am * sigmoid_f(m2g * g2f) + ab;
        if (D1) a1 = am * sigmoid_f(m2g * g1f) + ab;
        if (D0) a0 = am * sigmoid_f(m2g * g0f) + ab;
        // phase 3: one gather round (9 bpermutes in flight)
        float f2, q2, o2, f1, q1, o1, f0, q0, o0;
        if (D2) { f2 = __shfl(a2, lane + 10); q2 = __shfl(a2, lane + 20); o2 = __shfl(a2, lane + 30); }
        if (D1) { f1 = __shfl(a1, lane + 10); q1 = __shfl(a1, lane + 20); o1 = __shfl(a1, lane + 30); }
        if (D0) { f0 = __shfl(a0, lane + 10); q0 = __shfl(a0, lane + 20); o0 = __shfl(a0, lane + 30); }
        // phase 4: cell updates (valid in lanes 0..9)
        float h2 = 0.f, h1 = 0.f, h0 = 0.f;
        if (D2) { c2 = f2 * c2 + a2 * q2; h2 = o2 * tanh_f(c2); }
        if (D1) { c1 = f1 * c1 + a1 * q1; h1 = o1 * tanh_f(c1); }
        if (D0) { c0 = f0 * c0 + a0 * q0; h0 = o0 * tanh_f(c0); }
        // phase 5: one broadcast round (30 bpermutes in flight)
        #pragma unroll
        for (int k = 0; k < 10; ++k) {
            if (D2) hb2[k] = __shfl(h2, k);
            if (D1) hb1[k] = __shfl(h1, k);
            if (D0) hb0[k] = __shfl(h0, k);
        }
    };

    loadx(xc, 0);
    loadx(xn, 1);
    tick(true, false, false); cpx();        // tau=0
    loadx(xn, 2);
    tick(true, true, false); cpx();         // tau=1
    for (int tau = 2; tau < 63; ++tau) {    // tau=2..62: full pipeline
        loadx(xn, tau + 1);
        tick(true, true, true);
        cpx();
    }
    tick(true, true, true);                 // tau=63 (uses x63)
    tick(false, true, true);                // tau=64
    tick(false, false, true);               // tau=65

    // tv = h_n(layer2) + h_n(layer1)
    float tv[10];
    #pragma unroll
    for (int k = 0; k < 10; ++k) tv[k] = hb1[k] + hb2[k];

    // ---- fused per-row MLP: 10 ->128 ->256 ->64 ->7 ----
    {
        const v2f* w0 = (const v2f*)(L1W + lane * 10);
        const v2f* w1 = (const v2f*)(L1W + (lane + 64) * 10);
        float a0 = L1b[lane] + dot10(w0, tv);
        float a1 = L1b[lane + 64] + dot10(w1, tv);
        m1[lane] = lrelu(a0);
        m1[lane + 64] = lrelu(a1);
    }
    __asm__ __volatile__("" ::: "memory");
    {
        float acc[4];
        #pragma unroll
        for (int q = 0; q < 4; ++q) acc[q] = L2b[lane + 64 * q];
        for (int k = 0; k < 128; k += 4) {
            float4 hv = *(const float4*)(m1 + k);
            #pragma unroll
            for (int q = 0; q < 4; ++q) {
                float4 wv = *(const float4*)(L2W + (size_t)(lane + 64 * q) * 128 + k);
                acc[q] = fmaf(wv.x, hv.x, acc[q]);
                acc[q] = fmaf(wv.y, hv.y, acc[q]);
                acc[q] = fmaf(wv.z, hv.z, acc[q]);
                acc[q] = fmaf(wv.w, hv.w, acc[q]);
            }
        }
        #pragma unroll
        for (int q = 0; q < 4; ++q) m2b[lane + 64 * q] = lrelu(acc[q]);
    }
    __asm__ __volatile__("" ::: "memory");
    {
        float acc = L3b[lane];
        for (int k = 0; k < 256; k += 4) {
            float4 hv = *(const float4*)(m2b + k);
            float4 wv = *(const float4*)(L3W + (size_t)lane * 256 + k);
            acc = fmaf(wv.x, hv.x, acc);
            acc = fmaf(wv.y, hv.y, acc);
            acc = fmaf(wv.z, hv.z, acc);
            acc = fmaf(wv.w, hv.w, acc);
        }
        m3[lane] = lrelu(acc);
    }
    __asm__ __volatile__("" ::: "memory");
    if (lane < 7) {
        float acc = L4b[lane];
        #pragma unroll
        for (int k = 0; k < 64; k += 4) {
            float4 hv = *(const float4*)(m3 + k);
            float4 wv = *(const float4*)(L4W + lane * 64 + k);
            acc = fmaf(wv.x, hv.x, acc);
            acc = fmaf(wv.y, hv.y, acc);
            acc = fmaf(wv.z, hv.z, acc);
            acc = fmaf(wv.w, hv.w, acc);
        }
        out[ti * 7 + lane] = acc;
    }
}

// ---------------------------------------------------------------------------
extern "C" void kernel_launch(void* const* d_in, const int* in_sizes, int n_in,
                              void* d_out, int out_size, void* d_ws, size_t ws_size,
                              hipStream_t stream)
{
    const float* data_in = (const float*)d_in[0];
    const float* W1 = (const float*)d_in[1];
    const float* b1 = (const float*)d_in[2];
    const float* W2 = (const float*)d_in[3];
    const float* b2 = (const float*)d_in[4];
    const float* W3 = (const float*)d_in[5];
    const float* b3 = (const float*)d_in[6];
    const float* fWih = (const float*)d_in[7];
    const float* fWhh = (const float*)d_in[8];
    const float* fb = (const float*)d_in[9];
    const float* tWih = (const float*)d_in[10];
    const float* tWhh = (const float*)d_in[11];
    const float* tb = (const float*)d_in[12];
    const float* L1W = (const float*)d_in[13];
    const float* L1b = (const float*)d_in[14];
    const float* L2W = (const float*)d_in[15];
    const float* L2b = (const float*)d_in[16];
    const float* L3W = (const float*)d_in[17];
    const float* L3b = (const float*)d_in[18];
    const float* L4W = (const float*)d_in[19];
    const float* L4b = (const float*)d_in[20];

    float* xseq = (float*)d_ws;            // 4096*180 floats
    float* fv = xseq + 4096 * 180;         // 4096*10 floats
    float* outp = (float*)d_out;           // 64*7 floats

    conv_kernel<<<4096, 256, 0, stream>>>(data_in, W1, b1, W2, b2, W3, b3, xseq);
    flow_lstm_kernel<<<256, 256, 0, stream>>>(xseq, fWih, fWhh, fb, fv);
    trace_mlp_kernel<<<64, 64, 0, stream>>>(fv, tWih, tWhh, tb,
                                            L1W, L1b, L2W, L2b, L3W, L3b,
                                            L4W, L4b, outp);
}

// Round 3
// 205.222 us; speedup vs baseline: 1.0110x; 1.0110x over previous
//
#include <hip/hip_runtime.h>
#include <math.h>

#define LEAK 0.01f

typedef float v2f __attribute__((ext_vector_type(2)));

// pin a value into VGPR(s): makes compiler rematerialization impossible
#define PIN(x) asm volatile("" : "+v"(x))

__device__ __forceinline__ float lrelu(float x) { return fmaxf(x, LEAK * x); }
__device__ __forceinline__ float fast_rcp(float x) { return __builtin_amdgcn_rcpf(x); }
__device__ __forceinline__ float sigmoid_f(float x) {
    return fast_rcp(1.0f + exp2f(-1.44269504f * x));
}
__device__ __forceinline__ float tanh_f(float x) {
    return 2.0f * fast_rcp(1.0f + exp2f(-2.88539008f * x)) - 1.0f;
}

// dot of 10 via 5 packed v_pk_fma_f32
__device__ __forceinline__ float dot10(const v2f w[5], const float h[10]) {
    v2f acc = w[0] * (v2f){h[0], h[1]};
    acc += w[1] * (v2f){h[2], h[3]};
    acc += w[2] * (v2f){h[4], h[5]};
    acc += w[3] * (v2f){h[6], h[7]};
    acc += w[4] * (v2f){h[8], h[9]};
    return acc.x + acc.y;
}

#define L1C 508
#define L1P 170
#define L2C 166
#define L2P 56
#define L3C 52
#define L3P 18
#define TT 18

// ---------------------------------------------------------------------------
// K1: per-flow conv1d x3 (+lrelu, +maxpool3 fused; pool windows are disjoint)
// one block = one flow. Sliding-window register reuse for conv1; conv2
// streams y1 rows (5 live v2f) to fit the 128-VGPR cap at 4 blocks/CU.
// ---------------------------------------------------------------------------
__global__ __launch_bounds__(256, 4) void conv_kernel(
    const float* __restrict__ in,
    const float* __restrict__ W1, const float* __restrict__ b1,
    const float* __restrict__ W2, const float* __restrict__ b2,
    const float* __restrict__ W3, const float* __restrict__ b3,
    float* __restrict__ xseq)
{
    __shared__ __align__(16) float xsraw[24 + 1536 + 24];
    __shared__ __align__(16) float y1raw[16 + L1P * 10 + 32];
    __shared__ __align__(16) float y2raw[8 + L2P * 6 + 24];
    float* xs = xsraw + 24;   // xs[l*3+p]
    float* y1 = y1raw + 16;   // y1[o*10+co]
    float* y2 = y2raw + 8;    // y2[o*6+co]  (stride 6, b64-aligned rows)

    const int tid = threadIdx.x;
    const int b = blockIdx.x;

    { // load input, 1536 floats, coalesced float4
        const float4* src = (const float4*)(in + (size_t)b * 1536);
        float4* dst4 = (float4*)xs;
        for (int i = tid; i < 384; i += 256) dst4[i] = src[i];
    }
    __syncthreads();

    // ---- conv1 (3->10, k5) + lrelu + pool3 -> y1[170][10] ----
    {
        const int co = tid % 10;
        const int ob = tid / 10;            // 0..24 for tid<250
        if (tid < 250) {
            float w[15];
            #pragma unroll
            for (int q = 0; q < 15; ++q) w[q] = W1[co * 15 + q];
            const float bias = b1[co];
            const int o0 = ob * 7;
            int sb = 3 * o0 - 1;
            float win[21];
            #pragma unroll
            for (int q = 0; q < 21; ++q) win[q] = xs[3 * sb + q];
            #pragma unroll
            for (int r = 0; r < 7; ++r) {
                const int o = o0 + r;
                if (o < L1P) {
                    float a0 = bias, a1 = bias, a2 = bias;
                    #pragma unroll
                    for (int p = 0; p < 3; ++p) {
                        #pragma unroll
                        for (int k = 0; k < 5; ++k) {
                            const float wv = w[p * 5 + k];
                            a0 = fmaf(wv, win[3 * k + p], a0);
                            a1 = fmaf(wv, win[3 * (k + 1) + p], a1);
                            a2 = fmaf(wv, win[3 * (k + 2) + p], a2);
                        }
                    }
                    float best = -3.0e38f;
                    if (sb >= 0)        best = fmaxf(best, lrelu(a0));
                    best = fmaxf(best, lrelu(a1));
                    if (sb + 2 < L1C)   best = fmaxf(best, lrelu(a2));
                    y1[o * 10 + co] = best;
                }
                if (r < 6 && o + 1 < L1P) {
                    #pragma unroll
                    for (int q = 0; q < 12; ++q) win[q] = win[q + 9];
                    #pragma unroll
                    for (int q = 0; q < 9; ++q) win[12 + q] = xs[3 * sb + 21 + q];
                    sb += 3;
                }
            }
        }
    }
    __syncthreads();

    // ---- conv2 (10->5, k5) + lrelu + pool3 -> y2[56][6-stride] ----
    // stream rows: only 5 v2f of y1 live at a time.
    {
        const int co = tid % 5;
        const int ob = tid / 5;             // 0..50 for tid<255
        v2f wv2[25];                        // wv2[c2*5+k] = (w[2c2][k], w[2c2+1][k])
        #pragma unroll
        for (int c2 = 0; c2 < 5; ++c2)
            #pragma unroll
            for (int k = 0; k < 5; ++k)
                wv2[c2 * 5 + k] = (v2f){W2[co * 50 + (2 * c2) * 5 + k],
                                        W2[co * 50 + (2 * c2 + 1) * 5 + k]};
        const float bias = b2[co];
        if (tid < 255) {
            for (int r = 0; r < 2; ++r) {
                const int o = ob + 51 * r;
                if (o < L2P) {
                    const int t0 = 3 * o - 1;
                    v2f v0 = {0.f, 0.f}, v1 = {0.f, 0.f}, v2 = {0.f, 0.f};
                    #pragma unroll
                    for (int m = 0; m < 7; ++m) {
                        v2f rows5[5];
                        const v2f* pr = (const v2f*)(y1 + (t0 + m) * 10);
                        #pragma unroll
                        for (int c2 = 0; c2 < 5; ++c2) rows5[c2] = pr[c2];
                        #pragma unroll
                        for (int c2 = 0; c2 < 5; ++c2) {
                            if (m < 5)           v0 += wv2[c2 * 5 + m] * rows5[c2];
                            if (m >= 1 && m <= 5) v1 += wv2[c2 * 5 + m - 1] * rows5[c2];
                            if (m >= 2)          v2 += wv2[c2 * 5 + m - 2] * rows5[c2];
                        }
                    }
                    const float a0 = bias + v0.x + v0.y;
                    const float a1 = bias + v1.x + v1.y;
                    const float a2 = bias + v2.x + v2.y;
                    float best = -3.0e38f;
                    if (t0 >= 0)        best = fmaxf(best, lrelu(a0));
                    best = fmaxf(best, lrelu(a1));
                    if (t0 + 2 < L2C)   best = fmaxf(best, lrelu(a2));
                    y2[o * 6 + co] = best;
                }
            }
        }
    }
    __syncthreads();

    // ---- conv3 (5->10, k5) + lrelu + pool3 -> xseq[b][t=o][j=co] ----
    {
        const int co = tid % 10;
        const int o = tid / 10;             // 0..25
        if (o < L3P) {
            v2f wv3[10];
            float ws3[5];
            #pragma unroll
            for (int c2 = 0; c2 < 2; ++c2)
                #pragma unroll
                for (int k = 0; k < 5; ++k)
                    wv3[c2 * 5 + k] = (v2f){W3[co * 25 + (2 * c2) * 5 + k],
                                            W3[co * 25 + (2 * c2 + 1) * 5 + k]};
            #pragma unroll
            for (int k = 0; k < 5; ++k) ws3[k] = W3[co * 25 + 20 + k];
            const float bias = b3[co];
            const int t0 = 3 * o - 1;
            v2f v0 = {0.f, 0.f}, v1 = {0.f, 0.f}, v2 = {0.f, 0.f};
            float s0 = 0.f, s1 = 0.f, s2 = 0.f;
            #pragma unroll
            for (int m = 0; m < 7; ++m) {
                const float* base = y2 + (t0 + m) * 6;
                v2f ra0 = ((const v2f*)base)[0];
                v2f ra1 = ((const v2f*)base)[1];
                float rcm = base[4];
                if (m < 5) {
                    v0 += wv3[m] * ra0; v0 += wv3[5 + m] * ra1;
                    s0 = fmaf(ws3[m], rcm, s0);
                }
                if (m >= 1 && m <= 5) {
                    v1 += wv3[m - 1] * ra0; v1 += wv3[5 + m - 1] * ra1;
                    s1 = fmaf(ws3[m - 1], rcm, s1);
                }
                if (m >= 2) {
                    v2 += wv3[m - 2] * ra0; v2 += wv3[5 + m - 2] * ra1;
                    s2 = fmaf(ws3[m - 2], rcm, s2);
                }
            }
            const float a0 = bias + s0 + v0.x + v0.y;
            const float a1 = bias + s1 + v1.x + v1.y;
            const float a2 = bias + s2 + v2.x + v2.y;
            float best = -3.0e38f;
            if (t0 >= 0)        best = fmaxf(best, lrelu(a0));
            best = fmaxf(best, lrelu(a1));
            if (t0 + 2 < L3C)   best = fmaxf(best, lrelu(a2));
            xseq[(size_t)b * 180 + o * 10 + co] = best;
        }
    }
}

// ---------------------------------------------------------------------------
// K2: flow LSTM (3 layers, T=18, H=10) over 4096 flows.
// 16 lanes per flow; lane j owns hidden unit j (all 4 gates, packed dots).
// Weights PINNED in VGPRs (no remat inside the recurrence).
// ---------------------------------------------------------------------------
__global__ __launch_bounds__(256, 2) void flow_lstm_kernel(
    const float* __restrict__ xseq,
    const float* __restrict__ fWih, const float* __restrict__ fWhh,
    const float* __restrict__ fb,
    float* __restrict__ fv)
{
    __shared__ __align__(16) float sbuf[3][16 * 18 * 10];
    const int tid = threadIdx.x;
    const int blk = blockIdx.x;

    {
        const float* src = xseq + (size_t)blk * 2880;
        for (int i = tid; i < 2880; i += 256) sbuf[0][i] = src[i];
    }
    __syncthreads();

    const int el = tid >> 4;                 // local flow 0..15
    const int j = tid & 15;
    const int jj = (j < 10) ? j : 0;
    const int base = el * 180;
    const int lane = tid & 63;
    const int gbase = lane & 48;             // 16-lane group base within wave

    float fv_acc = 0.0f;

    for (int l = 0; l < 3; ++l) {
        const float* Wi = fWih + l * 400;
        const float* Wh = fWhh + l * 400;
        const float* bb = fb + l * 40;
        v2f wi0[5], wi1[5], wi2[5], wi3[5], wh0[5], wh1[5], wh2[5], wh3[5];
        #pragma unroll
        for (int k = 0; k < 5; ++k) {
            wi0[k] = ((const v2f*)(Wi + jj * 10))[k];
            wi1[k] = ((const v2f*)(Wi + (10 + jj) * 10))[k];
            wi2[k] = ((const v2f*)(Wi + (20 + jj) * 10))[k];
            wi3[k] = ((const v2f*)(Wi + (30 + jj) * 10))[k];
            wh0[k] = ((const v2f*)(Wh + jj * 10))[k];
            wh1[k] = ((const v2f*)(Wh + (10 + jj) * 10))[k];
            wh2[k] = ((const v2f*)(Wh + (20 + jj) * 10))[k];
            wh3[k] = ((const v2f*)(Wh + (30 + jj) * 10))[k];
        }
        #pragma unroll
        for (int k = 0; k < 5; ++k) {
            PIN(wi0[k]); PIN(wi1[k]); PIN(wi2[k]); PIN(wi3[k]);
            PIN(wh0[k]); PIN(wh1[k]); PIN(wh2[k]); PIN(wh3[k]);
        }
        float bi = bb[jj], bf = bb[10 + jj], bg = bb[20 + jj], bo = bb[30 + jj];
        PIN(bi); PIN(bf); PIN(bg); PIN(bo);

        const float* inb = sbuf[l];
        float* outb = sbuf[(l + 1) % 3];
        float c = 0.0f, hj = 0.0f;
        float h[10], xc[10], xn[10];
        #pragma unroll
        for (int k = 0; k < 10; ++k) h[k] = 0.0f;
        {
            const v2f* p = (const v2f*)(inb + base);
            #pragma unroll
            for (int k = 0; k < 5; ++k) { v2f v = p[k]; xc[2*k] = v.x; xc[2*k+1] = v.y; }
        }

        for (int t = 0; t < TT; ++t) {
            if (t + 1 < TT) {
                const v2f* p = (const v2f*)(inb + base + (t + 1) * 10);
                #pragma unroll
                for (int k = 0; k < 5; ++k) { v2f v = p[k]; xn[2*k] = v.x; xn[2*k+1] = v.y; }
            }
            float gi = bi + dot10(wi0, xc) + dot10(wh0, h);
            float gf = bf + dot10(wi1, xc) + dot10(wh1, h);
            float gg = bg + dot10(wi2, xc) + dot10(wh2, h);
            float go = bo + dot10(wi3, xc) + dot10(wh3, h);
            const float ai = sigmoid_f(gi), af = sigmoid_f(gf);
            const float ag = tanh_f(gg),    ao = sigmoid_f(go);
            c = af * c + ai * ag;
            hj = ao * tanh_f(c);
            if (j < 10) outb[base + t * 10 + j] = hj;   // history for next layer
            #pragma unroll
            for (int k = 0; k < 10; ++k) h[k] = __shfl(hj, gbase + k);
            #pragma unroll
            for (int k = 0; k < 10; ++k) xc[k] = xn[k];
        }
        if (l >= 1) fv_acc += hj;
        __asm__ __volatile__("" ::: "memory");
    }
    if (j < 10) fv[(size_t)(blk * 16 + el) * 10 + j] = fv_acc;
}

// ---------------------------------------------------------------------------
// K3: trace LSTM (3 layers, T=64, H=10) for 64 rows + fused per-row MLP.
// One wave per row; phase-fused software-pipelined layers. Weights PINNED in
// VGPRs; __launch_bounds__(64,1) lifts the register cap so nothing is
// rematerialized from memory inside the 66-tick recurrence.
// ---------------------------------------------------------------------------
__global__ __launch_bounds__(64, 1) void trace_mlp_kernel(
    const float* __restrict__ fv,
    const float* __restrict__ tWih, const float* __restrict__ tWhh,
    const float* __restrict__ tb,
    const float* __restrict__ L1W, const float* __restrict__ L1b,
    const float* __restrict__ L2W, const float* __restrict__ L2b,
    const float* __restrict__ L3W, const float* __restrict__ L3b,
    const float* __restrict__ L4W, const float* __restrict__ L4b,
    float* __restrict__ out)
{
    __shared__ __align__(16) float xrow[640];
    __shared__ __align__(16) float m1[128];
    __shared__ __align__(16) float m2b[256];
    __shared__ __align__(16) float m3[64];

    const int lane = threadIdx.x;
    const int ti = blockIdx.x;

    {
        const float4* src = (const float4*)(fv + (size_t)ti * 640);
        float4* dst = (float4*)xrow;
        for (int i = lane; i < 160; i += 64) dst[i] = src[i];
    }
    __asm__ __volatile__("" ::: "memory");   // same-wave DS ordering

    const int gt = lane / 10;                 // 0:i 1:f 2:g 3:o (lanes<40)
    const bool isg = (gt == 2);
    const float m2g = isg ? 2.0f : 1.0f;      // tanh(x)=2*sig(2x)-1
    const float am = isg ? 2.0f : 1.0f;
    const float ab = isg ? -1.0f : 0.0f;

    const int r = (lane < 40) ? lane : 0;
    v2f wi0[5], wh0[5], wi1[5], wh1[5], wi2[5], wh2[5];
    #pragma unroll
    for (int k = 0; k < 5; ++k) {
        wi0[k] = ((const v2f*)(tWih + r * 10))[k];
        wh0[k] = ((const v2f*)(tWhh + r * 10))[k];
        wi1[k] = ((const v2f*)(tWih + 400 + r * 10))[k];
        wh1[k] = ((const v2f*)(tWhh + 400 + r * 10))[k];
        wi2[k] = ((const v2f*)(tWih + 800 + r * 10))[k];
        wh2[k] = ((const v2f*)(tWhh + 800 + r * 10))[k];
    }
    #pragma unroll
    for (int k = 0; k < 5; ++k) {
        PIN(wi0[k]); PIN(wh0[k]); PIN(wi1[k]);
        PIN(wh1[k]); PIN(wi2[k]); PIN(wh2[k]);
    }
    float bs0 = tb[r], bs1 = tb[40 + r], bs2 = tb[80 + r];
    PIN(bs0); PIN(bs1); PIN(bs2);

    float hb0[10], hb1[10], hb2[10];
    #pragma unroll
    for (int k = 0; k < 10; ++k) { hb0[k] = 0.0f; hb1[k] = 0.0f; hb2[k] = 0.0f; }
    float c0 = 0.0f, c1 = 0.0f, c2 = 0.0f;

    float xc[10], xn[10];
    auto loadx = [&](float* d, int t) __attribute__((always_inline)) {
        const v2f* p = (const v2f*)(xrow + t * 10);
        #pragma unroll
        for (int k = 0; k < 5; ++k) { v2f v = p[k]; d[2*k] = v.x; d[2*k+1] = v.y; }
    };
    auto cpx = [&]() __attribute__((always_inline)) {
        #pragma unroll
        for (int k = 0; k < 10; ++k) xc[k] = xn[k];
    };
    auto tick = [&](bool D0, bool D1, bool D2) __attribute__((always_inline)) {
        // phase 1: gate pre-activations (all reads are last-tick state)
        float g0f = 0.f, g1f = 0.f, g2f = 0.f;
        if (D2) g2f = bs2 + dot10(wi2, hb1) + dot10(wh2, hb2);
        if (D1) g1f = bs1 + dot10(wi1, hb0) + dot10(wh1, hb1);
        if (D0) g0f = bs0 + dot10(wi0, xc) + dot10(wh0, hb0);
        // phase 2: activations
        float a0 = 0.f, a1 = 0.f, a2 = 0.f;
        if (D2) a2 = am * sigmoid_f(m2g * g2f) + ab;
        if (D1) a1 = am * sigmoid_f(m2g * g1f) + ab;
        if (D0) a0 = am * sigmoid_f(m2g * g0f) + ab;
        // phase 3: one gather round (9 bpermutes in flight)
        float f2, q2, o2, f1, q1, o1, f0, q0, o0;
        if (D2) { f2 = __shfl(a2, lane + 10); q2 = __shfl(a2, lane + 20); o2 = __shfl(a2, lane + 30); }
        if (D1) { f1 = __shfl(a1, lane + 10); q1 = __shfl(a1, lane + 20); o1 = __shfl(a1, lane + 30); }
        if (D0) { f0 = __shfl(a0, lane + 10); q0 = __shfl(a0, lane + 20); o0 = __shfl(a0, lane + 30); }
        // phase 4: cell updates (valid in lanes 0..9)
        float h2 = 0.f, h1 = 0.f, h0 = 0.f;
        if (D2) { c2 = f2 * c2 + a2 * q2; h2 = o2 * tanh_f(c2); }
        if (D1) { c1 = f1 * c1 + a1 * q1; h1 = o1 * tanh_f(c1); }
        if (D0) { c0 = f0 * c0 + a0 * q0; h0 = o0 * tanh_f(c0); }
        // phase 5: one broadcast round (30 bpermutes in flight)
        #pragma unroll
        for (int k = 0; k < 10; ++k) {
            if (D2) hb2[k] = __shfl(h2, k);
            if (D1) hb1[k] = __shfl(h1, k);
            if (D0) hb0[k] = __shfl(h0, k);
        }
    };

    loadx(xc, 0);
    loadx(xn, 1);
    tick(true, false, false); cpx();        // tau=0
    loadx(xn, 2);
    tick(true, true, false); cpx();         // tau=1
    for (int tau = 2; tau < 63; ++tau) {    // tau=2..62: full pipeline
        loadx(xn, tau + 1);
        tick(true, true, true);
        cpx();
    }
    tick(true, true, true);                 // tau=63 (uses x63)
    tick(false, true, true);                // tau=64
    tick(false, false, true);               // tau=65

    // tv = h_n(layer2) + h_n(layer1)
    float tv[10];
    #pragma unroll
    for (int k = 0; k < 10; ++k) tv[k] = hb1[k] + hb2[k];

    // ---- fused per-row MLP: 10 ->128 ->256 ->64 ->7 ----
    {
        const v2f* w0 = (const v2f*)(L1W + lane * 10);
        const v2f* w1 = (const v2f*)(L1W + (lane + 64) * 10);
        float a0 = L1b[lane] + dot10(w0, tv);
        float a1 = L1b[lane + 64] + dot10(w1, tv);
        m1[lane] = lrelu(a0);
        m1[lane + 64] = lrelu(a1);
    }
    __asm__ __volatile__("" ::: "memory");
    {
        float acc[4];
        #pragma unroll
        for (int q = 0; q < 4; ++q) acc[q] = L2b[lane + 64 * q];
        for (int k = 0; k < 128; k += 4) {
            float4 hv = *(const float4*)(m1 + k);
            #pragma unroll
            for (int q = 0; q < 4; ++q) {
                float4 wv = *(const float4*)(L2W + (size_t)(lane + 64 * q) * 128 + k);
                acc[q] = fmaf(wv.x, hv.x, acc[q]);
                acc[q] = fmaf(wv.y, hv.y, acc[q]);
                acc[q] = fmaf(wv.z, hv.z, acc[q]);
                acc[q] = fmaf(wv.w, hv.w, acc[q]);
            }
        }
        #pragma unroll
        for (int q = 0; q < 4; ++q) m2b[lane + 64 * q] = lrelu(acc[q]);
    }
    __asm__ __volatile__("" ::: "memory");
    {
        float acc = L3b[lane];
        for (int k = 0; k < 256; k += 4) {
            float4 hv = *(const float4*)(m2b + k);
            float4 wv = *(const float4*)(L3W + (size_t)lane * 256 + k);
            acc = fmaf(wv.x, hv.x, acc);
            acc = fmaf(wv.y, hv.y, acc);
            acc = fmaf(wv.z, hv.z, acc);
            acc = fmaf(wv.w, hv.w, acc);
        }
        m3[lane] = lrelu(acc);
    }
    __asm__ __volatile__("" ::: "memory");
    if (lane < 7) {
        float acc = L4b[lane];
        #pragma unroll
        for (int k = 0; k < 64; k += 4) {
            float4 hv = *(const float4*)(m3 + k);
            float4 wv = *(const float4*)(L4W + lane * 64 + k);
            acc = fmaf(wv.x, hv.x, acc);
            acc = fmaf(wv.y, hv.y, acc);
            acc = fmaf(wv.z, hv.z, acc);
            acc = fmaf(wv.w, hv.w, acc);
        }
        out[ti * 7 + lane] = acc;
    }
}

// ---------------------------------------------------------------------------
extern "C" void kernel_launch(void* const* d_in, const int* in_sizes, int n_in,
                              void* d_out, int out_size, void* d_ws, size_t ws_size,
                              hipStream_t stream)
{
    const float* data_in = (const float*)d_in[0];
    const float* W1 = (const float*)d_in[1];
    const float* b1 = (const float*)d_in[2];
    const float* W2 = (const float*)d_in[3];
    const float* b2 = (const float*)d_in[4];
    const float* W3 = (const float*)d_in[5];
    const float* b3 = (const float*)d_in[6];
    const float* fWih = (const float*)d_in[7];
    const float* fWhh = (const float*)d_in[8];
    const float* fb = (const float*)d_in[9];
    const float* tWih = (const float*)d_in[10];
    const float* tWhh = (const float*)d_in[11];
    const float* tb = (const float*)d_in[12];
    const float* L1W = (const float*)d_in[13];
    const float* L1b = (const float*)d_in[14];
    const float* L2W = (const float*)d_in[15];
    const float* L2b = (const float*)d_in[16];
    const float* L3W = (const float*)d_in[17];
    const float* L3b = (const float*)d_in[18];
    const float* L4W = (const float*)d_in[19];
    const float* L4b = (const float*)d_in[20];

    float* xseq = (float*)d_ws;            // 4096*180 floats
    float* fv = xseq + 4096 * 180;         // 4096*10 floats
    float* outp = (float*)d_out;           // 64*7 floats

    conv_kernel<<<4096, 256, 0, stream>>>(data_in, W1, b1, W2, b2, W3, b3, xseq);
    flow_lstm_kernel<<<256, 256, 0, stream>>>(xseq, fWih, fWhh, fb, fv);
    trace_mlp_kernel<<<64, 64, 0, stream>>>(fv, tWih, tWhh, tb,
                                            L1W, L1b, L2W, L2b, L3W, L3b,
                                            L4W, L4b, outp);
}

// Round 4
// 195.361 us; speedup vs baseline: 1.0620x; 1.0505x over previous
//
#include <hip/hip_runtime.h>
#include <math.h>

#define LEAK 0.01f

typedef float v2f __attribute__((ext_vector_type(2)));

__device__ __forceinline__ float lrelu(float x) { return fmaxf(x, LEAK * x); }
__device__ __forceinline__ float fast_rcp(float x) { return __builtin_amdgcn_rcpf(x); }
__device__ __forceinline__ float sigmoid_f(float x) {
    return fast_rcp(1.0f + exp2f(-1.44269504f * x));
}
__device__ __forceinline__ float tanh_f(float x) {
    return 2.0f * fast_rcp(1.0f + exp2f(-2.88539008f * x)) - 1.0f;
}
__device__ __forceinline__ float readlane_f(float v, int l) {
    return __int_as_float(__builtin_amdgcn_readlane(__float_as_int(v), l));
}

// ---- named-scalar helpers (NO arrays: guarantees SROA/register residency) ----
#define DECL5(p) v2f p##_0, p##_1, p##_2, p##_3, p##_4
#define LOAD5(p, src) do { const v2f* _s5 = (const v2f*)(src); \
    p##_0 = _s5[0]; p##_1 = _s5[1]; p##_2 = _s5[2]; p##_3 = _s5[3]; p##_4 = _s5[4]; } while (0)
#define CP5(d, s) do { d##_0 = s##_0; d##_1 = s##_1; d##_2 = s##_2; d##_3 = s##_3; d##_4 = s##_4; } while (0)
#define ZERO5(p) do { p##_0 = (v2f){0.f,0.f}; p##_1 = (v2f){0.f,0.f}; p##_2 = (v2f){0.f,0.f}; \
    p##_3 = (v2f){0.f,0.f}; p##_4 = (v2f){0.f,0.f}; } while (0)
// packed dot over 5 v2f pairs (v_pk_fma_f32)
#define DOT5(w, x) ((w##_0 * x##_0 + w##_1 * x##_1) + (w##_2 * x##_2 + w##_3 * x##_3) + w##_4 * x##_4)

// uniform (SGPR-resident) 10-vector
#define DECLU(u) float u##0, u##1, u##2, u##3, u##4, u##5, u##6, u##7, u##8, u##9
#define ZEROU(u) do { u##0=u##1=u##2=u##3=u##4=u##5=u##6=u##7=u##8=u##9=0.0f; } while (0)
#define RL10(u, v) do { \
    u##0 = readlane_f(v, 0); u##1 = readlane_f(v, 1); u##2 = readlane_f(v, 2); \
    u##3 = readlane_f(v, 3); u##4 = readlane_f(v, 4); u##5 = readlane_f(v, 5); \
    u##6 = readlane_f(v, 6); u##7 = readlane_f(v, 7); u##8 = readlane_f(v, 8); \
    u##9 = readlane_f(v, 9); } while (0)
// dot: VGPR weight pairs x SGPR uniform vector (1 SGPR operand per fma)
#define DOTU(w, u) (fmaf(w##_0.x, u##0, fmaf(w##_0.y, u##1, fmaf(w##_1.x, u##2, fmaf(w##_1.y, u##3, w##_2.x * u##4)))) \
                  + fmaf(w##_2.y, u##5, fmaf(w##_3.x, u##6, fmaf(w##_3.y, u##7, fmaf(w##_4.x, u##8, w##_4.y * u##9)))))

#define L1C 508
#define L1P 170
#define L2C 166
#define L2P 56
#define L3C 52
#define L3P 18
#define TT 18

// ---------------------------------------------------------------------------
// K1: per-flow conv1d x3 (+lrelu, +maxpool3 fused) — unchanged from R3.
// ---------------------------------------------------------------------------
__global__ __launch_bounds__(256, 4) void conv_kernel(
    const float* __restrict__ in,
    const float* __restrict__ W1, const float* __restrict__ b1,
    const float* __restrict__ W2, const float* __restrict__ b2,
    const float* __restrict__ W3, const float* __restrict__ b3,
    float* __restrict__ xseq)
{
    __shared__ __align__(16) float xsraw[24 + 1536 + 24];
    __shared__ __align__(16) float y1raw[16 + L1P * 10 + 32];
    __shared__ __align__(16) float y2raw[8 + L2P * 6 + 24];
    float* xs = xsraw + 24;
    float* y1 = y1raw + 16;
    float* y2 = y2raw + 8;

    const int tid = threadIdx.x;
    const int b = blockIdx.x;

    {
        const float4* src = (const float4*)(in + (size_t)b * 1536);
        float4* dst4 = (float4*)xs;
        for (int i = tid; i < 384; i += 256) dst4[i] = src[i];
    }
    __syncthreads();

    // ---- conv1 (3->10, k5) + lrelu + pool3 -> y1[170][10] ----
    {
        const int co = tid % 10;
        const int ob = tid / 10;
        if (tid < 250) {
            float w[15];
            #pragma unroll
            for (int q = 0; q < 15; ++q) w[q] = W1[co * 15 + q];
            const float bias = b1[co];
            const int o0 = ob * 7;
            int sb = 3 * o0 - 1;
            float win[21];
            #pragma unroll
            for (int q = 0; q < 21; ++q) win[q] = xs[3 * sb + q];
            #pragma unroll
            for (int r = 0; r < 7; ++r) {
                const int o = o0 + r;
                if (o < L1P) {
                    float a0 = bias, a1 = bias, a2 = bias;
                    #pragma unroll
                    for (int p = 0; p < 3; ++p) {
                        #pragma unroll
                        for (int k = 0; k < 5; ++k) {
                            const float wv = w[p * 5 + k];
                            a0 = fmaf(wv, win[3 * k + p], a0);
                            a1 = fmaf(wv, win[3 * (k + 1) + p], a1);
                            a2 = fmaf(wv, win[3 * (k + 2) + p], a2);
                        }
                    }
                    float best = -3.0e38f;
                    if (sb >= 0)        best = fmaxf(best, lrelu(a0));
                    best = fmaxf(best, lrelu(a1));
                    if (sb + 2 < L1C)   best = fmaxf(best, lrelu(a2));
                    y1[o * 10 + co] = best;
                }
                if (r < 6 && o + 1 < L1P) {
                    #pragma unroll
                    for (int q = 0; q < 12; ++q) win[q] = win[q + 9];
                    #pragma unroll
                    for (int q = 0; q < 9; ++q) win[12 + q] = xs[3 * sb + 21 + q];
                    sb += 3;
                }
            }
        }
    }
    __syncthreads();

    // ---- conv2 (10->5, k5) + lrelu + pool3 -> y2[56][6-stride] ----
    {
        const int co = tid % 5;
        const int ob = tid / 5;
        v2f wv2[25];
        #pragma unroll
        for (int c2 = 0; c2 < 5; ++c2)
            #pragma unroll
            for (int k = 0; k < 5; ++k)
                wv2[c2 * 5 + k] = (v2f){W2[co * 50 + (2 * c2) * 5 + k],
                                        W2[co * 50 + (2 * c2 + 1) * 5 + k]};
        const float bias = b2[co];
        if (tid < 255) {
            for (int r = 0; r < 2; ++r) {
                const int o = ob + 51 * r;
                if (o < L2P) {
                    const int t0 = 3 * o - 1;
                    v2f v0 = {0.f, 0.f}, v1 = {0.f, 0.f}, v2 = {0.f, 0.f};
                    #pragma unroll
                    for (int m = 0; m < 7; ++m) {
                        v2f rows5[5];
                        const v2f* pr = (const v2f*)(y1 + (t0 + m) * 10);
                        #pragma unroll
                        for (int c2 = 0; c2 < 5; ++c2) rows5[c2] = pr[c2];
                        #pragma unroll
                        for (int c2 = 0; c2 < 5; ++c2) {
                            if (m < 5)            v0 += wv2[c2 * 5 + m] * rows5[c2];
                            if (m >= 1 && m <= 5) v1 += wv2[c2 * 5 + m - 1] * rows5[c2];
                            if (m >= 2)           v2 += wv2[c2 * 5 + m - 2] * rows5[c2];
                        }
                    }
                    const float a0 = bias + v0.x + v0.y;
                    const float a1 = bias + v1.x + v1.y;
                    const float a2 = bias + v2.x + v2.y;
                    float best = -3.0e38f;
                    if (t0 >= 0)        best = fmaxf(best, lrelu(a0));
                    best = fmaxf(best, lrelu(a1));
                    if (t0 + 2 < L2C)   best = fmaxf(best, lrelu(a2));
                    y2[o * 6 + co] = best;
                }
            }
        }
    }
    __syncthreads();

    // ---- conv3 (5->10, k5) + lrelu + pool3 -> xseq ----
    {
        const int co = tid % 10;
        const int o = tid / 10;
        if (o < L3P) {
            v2f wv3[10];
            float ws3[5];
            #pragma unroll
            for (int c2 = 0; c2 < 2; ++c2)
                #pragma unroll
                for (int k = 0; k < 5; ++k)
                    wv3[c2 * 5 + k] = (v2f){W3[co * 25 + (2 * c2) * 5 + k],
                                            W3[co * 25 + (2 * c2 + 1) * 5 + k]};
            #pragma unroll
            for (int k = 0; k < 5; ++k) ws3[k] = W3[co * 25 + 20 + k];
            const float bias = b3[co];
            const int t0 = 3 * o - 1;
            v2f v0 = {0.f, 0.f}, v1 = {0.f, 0.f}, v2 = {0.f, 0.f};
            float s0 = 0.f, s1 = 0.f, s2 = 0.f;
            #pragma unroll
            for (int m = 0; m < 7; ++m) {
                const float* base = y2 + (t0 + m) * 6;
                v2f ra0 = ((const v2f*)base)[0];
                v2f ra1 = ((const v2f*)base)[1];
                float rcm = base[4];
                if (m < 5) {
                    v0 += wv3[m] * ra0; v0 += wv3[5 + m] * ra1;
                    s0 = fmaf(ws3[m], rcm, s0);
                }
                if (m >= 1 && m <= 5) {
                    v1 += wv3[m - 1] * ra0; v1 += wv3[5 + m - 1] * ra1;
                    s1 = fmaf(ws3[m - 1], rcm, s1);
                }
                if (m >= 2) {
                    v2 += wv3[m - 2] * ra0; v2 += wv3[5 + m - 2] * ra1;
                    s2 = fmaf(ws3[m - 2], rcm, s2);
                }
            }
            const float a0 = bias + s0 + v0.x + v0.y;
            const float a1 = bias + s1 + v1.x + v1.y;
            const float a2 = bias + s2 + v2.x + v2.y;
            float best = -3.0e38f;
            if (t0 >= 0)        best = fmaxf(best, lrelu(a0));
            best = fmaxf(best, lrelu(a1));
            if (t0 + 2 < L3C)   best = fmaxf(best, lrelu(a2));
            xseq[(size_t)b * 180 + o * 10 + co] = best;
        }
    }
}

// ---------------------------------------------------------------------------
// K2: flow LSTM (3 layers, T=18, H=10) over 4096 flows.
// 16 lanes/flow, lane j owns unit j (all 4 gates). ALL state in named
// scalars (no arrays, no lambdas) -> guaranteed register residency.
// ---------------------------------------------------------------------------
__global__ __launch_bounds__(256, 2) void flow_lstm_kernel(
    const float* __restrict__ xseq,
    const float* __restrict__ fWih, const float* __restrict__ fWhh,
    const float* __restrict__ fb,
    float* __restrict__ fv)
{
    __shared__ __align__(16) float sbuf[3][16 * 18 * 10];
    const int tid = threadIdx.x;
    const int blk = blockIdx.x;

    {
        const float* src = xseq + (size_t)blk * 2880;
        for (int i = tid; i < 2880; i += 256) sbuf[0][i] = src[i];
    }
    __syncthreads();

    const int el = tid >> 4;
    const int j = tid & 15;
    const int jj = (j < 10) ? j : 0;
    const int base = el * 180;
    const int lane = tid & 63;
    const int gbase = lane & 48;

    float fv_acc = 0.0f;

    for (int l = 0; l < 3; ++l) {
        const float* Wi = fWih + l * 400;
        const float* Wh = fWhh + l * 400;
        const float* bb = fb + l * 40;
        DECL5(wii); DECL5(wif); DECL5(wig); DECL5(wio);
        DECL5(whi); DECL5(whf); DECL5(whg); DECL5(who);
        LOAD5(wii, Wi + jj * 10);
        LOAD5(wif, Wi + (10 + jj) * 10);
        LOAD5(wig, Wi + (20 + jj) * 10);
        LOAD5(wio, Wi + (30 + jj) * 10);
        LOAD5(whi, Wh + jj * 10);
        LOAD5(whf, Wh + (10 + jj) * 10);
        LOAD5(whg, Wh + (20 + jj) * 10);
        LOAD5(who, Wh + (30 + jj) * 10);
        const float bi = bb[jj], bf = bb[10 + jj], bg = bb[20 + jj], bo = bb[30 + jj];

        const float* inb = sbuf[l];
        float* outb = sbuf[(l + 1) % 3];
        float c = 0.0f, hj = 0.0f;
        DECL5(hv); ZERO5(hv);
        DECL5(xc); DECL5(xn);
        LOAD5(xc, inb + base);

        for (int t = 0; t < TT; ++t) {
            if (t + 1 < TT) LOAD5(xn, inb + base + (t + 1) * 10);
            v2f ti_ = DOT5(wii, xc) + DOT5(whi, hv);
            v2f tf_ = DOT5(wif, xc) + DOT5(whf, hv);
            v2f tg_ = DOT5(wig, xc) + DOT5(whg, hv);
            v2f to_ = DOT5(wio, xc) + DOT5(who, hv);
            const float ai = sigmoid_f(bi + ti_.x + ti_.y);
            const float af = sigmoid_f(bf + tf_.x + tf_.y);
            const float ag = tanh_f(bg + tg_.x + tg_.y);
            const float ao = sigmoid_f(bo + to_.x + to_.y);
            c = af * c + ai * ag;
            hj = ao * tanh_f(c);
            if (j < 10) outb[base + t * 10 + j] = hj;   // history for next layer
            hv_0 = (v2f){__shfl(hj, gbase + 0), __shfl(hj, gbase + 1)};
            hv_1 = (v2f){__shfl(hj, gbase + 2), __shfl(hj, gbase + 3)};
            hv_2 = (v2f){__shfl(hj, gbase + 4), __shfl(hj, gbase + 5)};
            hv_3 = (v2f){__shfl(hj, gbase + 6), __shfl(hj, gbase + 7)};
            hv_4 = (v2f){__shfl(hj, gbase + 8), __shfl(hj, gbase + 9)};
            CP5(xc, xn);
        }
        if (l >= 1) fv_acc += hj;
        __asm__ __volatile__("" ::: "memory");   // order LDS history vs next layer
    }
    if (j < 10) fv[(size_t)(blk * 16 + el) * 10 + j] = fv_acc;
}

// ---------------------------------------------------------------------------
// K3: trace LSTM (3 layers, T=64, H=10), one wave per trace row, + fused MLP.
// h state is wave-uniform -> lives in SGPRs via v_readlane (no broadcast DS
// round). Per tick: dots -> activations -> ONE 9-bpermute gather -> cell
// update -> 30 readlanes. All state in named scalars.
// ---------------------------------------------------------------------------
__global__ __launch_bounds__(64, 1) void trace_mlp_kernel(
    const float* __restrict__ fv,
    const float* __restrict__ tWih, const float* __restrict__ tWhh,
    const float* __restrict__ tb,
    const float* __restrict__ L1W, const float* __restrict__ L1b,
    const float* __restrict__ L2W, const float* __restrict__ L2b,
    const float* __restrict__ L3W, const float* __restrict__ L3b,
    const float* __restrict__ L4W, const float* __restrict__ L4b,
    float* __restrict__ out)
{
    __shared__ __align__(16) float xrow[640];
    __shared__ __align__(16) float m1[128];
    __shared__ __align__(16) float m2b[256];
    __shared__ __align__(16) float m3[64];

    const int lane = threadIdx.x;
    const int ti = blockIdx.x;

    {
        const float4* src = (const float4*)(fv + (size_t)ti * 640);
        float4* dst = (float4*)xrow;
        for (int i = lane; i < 160; i += 64) dst[i] = src[i];
    }
    __asm__ __volatile__("" ::: "memory");

    const int gt = lane / 10;
    const bool isg = (gt == 2);
    const float m2g = isg ? 2.0f : 1.0f;      // tanh(x)=2*sig(2x)-1
    const float am = isg ? 2.0f : 1.0f;
    const float ab = isg ? -1.0f : 0.0f;

    const int r = (lane < 40) ? lane : 0;
    DECL5(wi0); DECL5(wh0); DECL5(wi1); DECL5(wh1); DECL5(wi2); DECL5(wh2);
    LOAD5(wi0, tWih + r * 10);
    LOAD5(wh0, tWhh + r * 10);
    LOAD5(wi1, tWih + 400 + r * 10);
    LOAD5(wh1, tWhh + 400 + r * 10);
    LOAD5(wi2, tWih + 800 + r * 10);
    LOAD5(wh2, tWhh + 800 + r * 10);
    const float bs0 = tb[r], bs1 = tb[40 + r], bs2 = tb[80 + r];

    DECLU(u0); DECLU(u1); DECLU(u2);          // h state, SGPR-resident
    ZEROU(u0); ZEROU(u1); ZEROU(u2);
    float c0 = 0.0f, c1 = 0.0f, c2 = 0.0f;
    DECL5(xc); DECL5(xn);

#define TICK(D0, D1, D2) do { \
    float g0_ = 0.f, g1_ = 0.f, g2_ = 0.f; \
    if (D2) g2_ = bs2 + DOTU(wi2, u1) + DOTU(wh2, u2); \
    if (D1) g1_ = bs1 + DOTU(wi1, u0) + DOTU(wh1, u1); \
    if (D0) { v2f ax_ = DOT5(wi0, xc); g0_ = bs0 + ax_.x + ax_.y + DOTU(wh0, u0); } \
    float a0_ = 0.f, a1_ = 0.f, a2_ = 0.f; \
    if (D2) a2_ = am * sigmoid_f(m2g * g2_) + ab; \
    if (D1) a1_ = am * sigmoid_f(m2g * g1_) + ab; \
    if (D0) a0_ = am * sigmoid_f(m2g * g0_) + ab; \
    float f2_ = 0.f, q2_ = 0.f, o2_ = 0.f; \
    float f1_ = 0.f, q1_ = 0.f, o1_ = 0.f; \
    float f0_ = 0.f, q0_ = 0.f, o0_ = 0.f; \
    if (D2) { f2_ = __shfl(a2_, lane + 10); q2_ = __shfl(a2_, lane + 20); o2_ = __shfl(a2_, lane + 30); } \
    if (D1) { f1_ = __shfl(a1_, lane + 10); q1_ = __shfl(a1_, lane + 20); o1_ = __shfl(a1_, lane + 30); } \
    if (D0) { f0_ = __shfl(a0_, lane + 10); q0_ = __shfl(a0_, lane + 20); o0_ = __shfl(a0_, lane + 30); } \
    if (D2) { c2 = f2_ * c2 + a2_ * q2_; float h_ = o2_ * tanh_f(c2); RL10(u2, h_); } \
    if (D1) { c1 = f1_ * c1 + a1_ * q1_; float h_ = o1_ * tanh_f(c1); RL10(u1, h_); } \
    if (D0) { c0 = f0_ * c0 + a0_ * q0_; float h_ = o0_ * tanh_f(c0); RL10(u0, h_); } \
} while (0)

    LOAD5(xc, xrow + 0);
    LOAD5(xn, xrow + 10);
    TICK(true, false, false); CP5(xc, xn);   // tau=0
    LOAD5(xn, xrow + 20);
    TICK(true, true, false); CP5(xc, xn);    // tau=1
    for (int tau = 2; tau < 63; ++tau) {     // tau=2..62
        LOAD5(xn, xrow + (tau + 1) * 10);
        TICK(true, true, true);
        CP5(xc, xn);
    }
    TICK(true, true, true);                  // tau=63 (uses x63)
    TICK(false, true, true);                 // tau=64
    TICK(false, false, true);                // tau=65
#undef TICK

    // tv = h_n(layer2) + h_n(layer1): wave-uniform
    DECLU(tv);
    tv0 = u10 + u20; tv1 = u11 + u21; tv2 = u12 + u22; tv3 = u13 + u23;
    tv4 = u14 + u24; tv5 = u15 + u25; tv6 = u16 + u26; tv7 = u17 + u27;
    tv8 = u18 + u28; tv9 = u19 + u29;

    // ---- fused per-row MLP: 10 ->128 ->256 ->64 ->7 ----
    {
        DECL5(w1a); DECL5(w1b);
        LOAD5(w1a, L1W + lane * 10);
        LOAD5(w1b, L1W + (lane + 64) * 10);
        float a0 = L1b[lane] + DOTU(w1a, tv);
        float a1 = L1b[lane + 64] + DOTU(w1b, tv);
        m1[lane] = lrelu(a0);
        m1[lane + 64] = lrelu(a1);
    }
    __asm__ __volatile__("" ::: "memory");
    {
        float acc0 = L2b[lane];
        float acc1 = L2b[lane + 64];
        float acc2 = L2b[lane + 128];
        float acc3 = L2b[lane + 192];
        for (int k = 0; k < 128; k += 4) {
            float4 hv = *(const float4*)(m1 + k);
            float4 w0 = *(const float4*)(L2W + (size_t)lane * 128 + k);
            float4 w1 = *(const float4*)(L2W + (size_t)(lane + 64) * 128 + k);
            float4 w2 = *(const float4*)(L2W + (size_t)(lane + 128) * 128 + k);
            float4 w3 = *(const float4*)(L2W + (size_t)(lane + 192) * 128 + k);
            acc0 = fmaf(w0.x, hv.x, acc0); acc0 = fmaf(w0.y, hv.y, acc0);
            acc0 = fmaf(w0.z, hv.z, acc0); acc0 = fmaf(w0.w, hv.w, acc0);
            acc1 = fmaf(w1.x, hv.x, acc1); acc1 = fmaf(w1.y, hv.y, acc1);
            acc1 = fmaf(w1.z, hv.z, acc1); acc1 = fmaf(w1.w, hv.w, acc1);
            acc2 = fmaf(w2.x, hv.x, acc2); acc2 = fmaf(w2.y, hv.y, acc2);
            acc2 = fmaf(w2.z, hv.z, acc2); acc2 = fmaf(w2.w, hv.w, acc2);
            acc3 = fmaf(w3.x, hv.x, acc3); acc3 = fmaf(w3.y, hv.y, acc3);
            acc3 = fmaf(w3.z, hv.z, acc3); acc3 = fmaf(w3.w, hv.w, acc3);
        }
        m2b[lane] = lrelu(acc0);
        m2b[lane + 64] = lrelu(acc1);
        m2b[lane + 128] = lrelu(acc2);
        m2b[lane + 192] = lrelu(acc3);
    }
    __asm__ __volatile__("" ::: "memory");
    {
        float acc = L3b[lane];
        for (int k = 0; k < 256; k += 4) {
            float4 hv = *(const float4*)(m2b + k);
            float4 wv = *(const float4*)(L3W + (size_t)lane * 256 + k);
            acc = fmaf(wv.x, hv.x, acc);
            acc = fmaf(wv.y, hv.y, acc);
            acc = fmaf(wv.z, hv.z, acc);
            acc = fmaf(wv.w, hv.w, acc);
        }
        m3[lane] = lrelu(acc);
    }
    __asm__ __volatile__("" ::: "memory");
    if (lane < 7) {
        float acc = L4b[lane];
        #pragma unroll
        for (int k = 0; k < 64; k += 4) {
            float4 hv = *(const float4*)(m3 + k);
            float4 wv = *(const float4*)(L4W + lane * 64 + k);
            acc = fmaf(wv.x, hv.x, acc);
            acc = fmaf(wv.y, hv.y, acc);
            acc = fmaf(wv.z, hv.z, acc);
            acc = fmaf(wv.w, hv.w, acc);
        }
        out[ti * 7 + lane] = acc;
    }
}

// ---------------------------------------------------------------------------
extern "C" void kernel_launch(void* const* d_in, const int* in_sizes, int n_in,
                              void* d_out, int out_size, void* d_ws, size_t ws_size,
                              hipStream_t stream)
{
    const float* data_in = (const float*)d_in[0];
    const float* W1 = (const float*)d_in[1];
    const float* b1 = (const float*)d_in[2];
    const float* W2 = (const float*)d_in[3];
    const float* b2 = (const float*)d_in[4];
    const float* W3 = (const float*)d_in[5];
    const float* b3 = (const float*)d_in[6];
    const float* fWih = (const float*)d_in[7];
    const float* fWhh = (const float*)d_in[8];
    const float* fb = (const float*)d_in[9];
    const float* tWih = (const float*)d_in[10];
    const float* tWhh = (const float*)d_in[11];
    const float* tb = (const float*)d_in[12];
    const float* L1W = (const float*)d_in[13];
    const float* L1b = (const float*)d_in[14];
    const float* L2W = (const float*)d_in[15];
    const float* L2b = (const float*)d_in[16];
    const float* L3W = (const float*)d_in[17];
    const float* L3b = (const float*)d_in[18];
    const float* L4W = (const float*)d_in[19];
    const float* L4b = (const float*)d_in[20];

    float* xseq = (float*)d_ws;            // 4096*180 floats
    float* fv = xseq + 4096 * 180;         // 4096*10 floats
    float* outp = (float*)d_out;           // 64*7 floats

    conv_kernel<<<4096, 256, 0, stream>>>(data_in, W1, b1, W2, b2, W3, b3, xseq);
    flow_lstm_kernel<<<256, 256, 0, stream>>>(xseq, fWih, fWhh, fb, fv);
    trace_mlp_kernel<<<64, 64, 0, stream>>>(fv, tWih, tWhh, tb,
                                            L1W, L1b, L2W, L2b, L3W, L3b,
                                            L4W, L4b, outp);
}